// Round 12
// baseline (394.186 us; speedup 1.0000x reference)
//
#include <hip/hip_runtime.h>
#include <hip/hip_bf16.h>

typedef __bf16 bf16x8 __attribute__((ext_vector_type(8)));
typedef float  f32x4  __attribute__((ext_vector_type(4)));

constexpr int B = 8, N = 4096, T = 128, D = 32;
constexpr float GAMMA = 0.001f;
constexpr float LOG2E = 1.4426950408889634f;
constexpr float K2 = -GAMMA * LOG2E;   // coeff on sq1 / sq2 (log2 domain)
constexpr float M2 = -2.0f * K2;       // coeff on dot

__device__ __forceinline__ float exp2_fast(float t) {
#if __has_builtin(__builtin_amdgcn_exp2f)
  return __builtin_amdgcn_exp2f(t);
#else
  return exp2f(t);
#endif
}

// deg-3 minimax for 2^t on [-2, 0]; abs err ~6.5e-4 (t provably in-range).
__device__ __forceinline__ float exp2_poly(float t) {
  return fmaf(fmaf(fmaf(0.0285860f, t, 0.2107500f), t, 0.6821055f), t,
              0.9993455f);
}

// ---------------------------------------------------------------------------
// Kernel 1 (MFMA proj): unchanged from r3-r11 (~4 us).
// ---------------------------------------------------------------------------
__global__ __launch_bounds__(256, 2) void proj_mfma(
    const float* __restrict__ x,  const float* __restrict__ W1,
    const float* __restrict__ b1, const float* __restrict__ W2,
    const float* __restrict__ b2,
    __bf16* __restrict__ p1b, __bf16* __restrict__ p2b,
    float* __restrict__ s1, float* __restrict__ e2) {
  __shared__ bf16x8 wlds[4][4][64];   // 16 KB, frag-ready
  const int tid  = threadIdx.x;
  const int lane = tid & 63;
  const int wid  = tid >> 6;
  const int lr   = lane & 15;
  const int lk   = lane >> 4;
  const int r0   = blockIdx.x * 64 + wid * 16;   // 0 .. B*N-1

  #pragma unroll
  for (int t = 0; t < 4; ++t) {
    const int e  = tid + t * 256;
    const int c  = e >> 8;
    const int s  = (e >> 6) & 3;
    const int ln = e & 63;
    const int llr = ln & 15, llk = ln >> 4;
    const float* Wp = (c < 2) ? W1 : W2;
    const int cc = (c * 16 + llr) & 31;
    bf16x8 v;
    #pragma unroll
    for (int j = 0; j < 8; ++j)
      v[j] = (__bf16)Wp[(s * 32 + llk * 8 + j) * D + cc];
    wlds[c][s][ln] = v;
  }
  __syncthreads();

  bf16x8 wf[4][4];
  #pragma unroll
  for (int c = 0; c < 4; ++c)
    #pragma unroll
    for (int s = 0; s < 4; ++s)
      wf[c][s] = wlds[c][s][lane];

  bf16x8 af[4];
  const float* xr = x + (size_t)(r0 + lr) * T;
  #pragma unroll
  for (int s = 0; s < 4; ++s) {
    const int t0 = s * 32 + lk * 8;
    const f32x4 v0 = *reinterpret_cast<const f32x4*>(xr + t0);
    const f32x4 v1 = *reinterpret_cast<const f32x4*>(xr + t0 + 4);
    #pragma unroll
    for (int j = 0; j < 4; ++j) {
      af[s][j]     = (__bf16)v0[j];
      af[s][4 + j] = (__bf16)v1[j];
    }
  }

  f32x4 pv[4];
  #pragma unroll
  for (int c = 0; c < 4; ++c) {
    const float* bp = (c < 2) ? b1 : b2;
    const float bv = bp[(c * 16 + lr) & 31];
    f32x4 accv = {bv, bv, bv, bv};
    #pragma unroll
    for (int s = 0; s < 4; ++s)
      accv = __builtin_amdgcn_mfma_f32_16x16x32_bf16(af[s], wf[c][s], accv, 0, 0, 0);
    pv[c] = accv;
  }

  #pragma unroll
  for (int c = 0; c < 2; ++c)
    #pragma unroll
    for (int r = 0; r < 4; ++r)
      p1b[(size_t)(r0 + lk * 4 + r) * D + c * 16 + lr] = (__bf16)(M2 * pv[c][r]);
  #pragma unroll
  for (int c = 2; c < 4; ++c)
    #pragma unroll
    for (int r = 0; r < 4; ++r)
      p2b[(size_t)(r0 + lk * 4 + r) * D + (c - 2) * 16 + lr] = (__bf16)pv[c][r];

  float q1[4], q2[4];
  #pragma unroll
  for (int r = 0; r < 4; ++r) {
    q1[r] = fmaf(pv[0][r], pv[0][r], pv[1][r] * pv[1][r]);
    q2[r] = fmaf(pv[2][r], pv[2][r], pv[3][r] * pv[3][r]);
  }
  #pragma unroll
  for (int m = 1; m < 16; m <<= 1)
    #pragma unroll
    for (int r = 0; r < 4; ++r) {
      q1[r] += __shfl_xor(q1[r], m, 64);
      q2[r] += __shfl_xor(q2[r], m, 64);
    }
  if (lr == 0) {
    #pragma unroll
    for (int r = 0; r < 4; ++r) {
      const int row = r0 + lk * 4 + r;
      s1[row] = K2 * q1[r];
      e2[row] = 0.125f * exp2_fast(K2 * q2[r]);
    }
  }
}

// ---------------------------------------------------------------------------
// Kernel 2 v12: 4-tile pipelined blocks (one cohort: 1024 blocks = 4/CU) +
// transposed MFMA (operands swapped) for dwordx4 stores.
//  - B-panel + E staged ONCE per block (34 KB LDS; B-stage traffic 4x lower)
//  - per tile: compute(t) -> loadA(t+1) -> sched_barrier -> store(t):
//    counted vmcnt lets tile-t stores drain under tile-(t+1) compute
//    (r10's overlap failed because the compiler sank loads below stores ->
//    vmcnt(0); sched_barrier(0) pins the issue order).
//  - mfma(Bf, A, S): D[col=lane&15 -> i, reg -> j] => lane owns 4 consecutive
//    output cols: stores 16 dword -> 4 dwordx4; E is a vector f32x4 read;
//    C-in is the lane-scalar s1[i] broadcast.
// ---------------------------------------------------------------------------
__global__ __launch_bounds__(256, 4) void fused_kernel(
    const __bf16* __restrict__ p1b, const __bf16* __restrict__ p2b,
    const float* __restrict__ s1,   const float* __restrict__ e2,
    float* __restrict__ out) {
  __shared__ __align__(16) __bf16 LB[B * 64 * 32];  // 32 KB, swizzled slots
  __shared__ __align__(16) float  LE[B * 64];       // 2 KB

  const int tid  = threadIdx.x;
  const int lane = tid & 63;
  const int wid  = tid >> 6;
  const int j0 = blockIdx.x * 64;                // col base (block)
  const int y0 = blockIdx.y * 256;               // row base (block, 4 tiles)
  const int lr = lane & 15;
  const int lk = lane >> 4;

  bf16x8 A[B];
  float  Sv[B];
  auto loadAS = [&](int t) __attribute__((always_inline)) {
    const int i0 = y0 + t * 64 + wid * 16;
    #pragma unroll
    for (int b = 0; b < B; ++b)
      A[b] = *reinterpret_cast<const bf16x8*>(
          p1b + ((size_t)b * N + i0 + lr) * D + lk * 8);
    #pragma unroll
    for (int b = 0; b < B; ++b)
      Sv[b] = s1[(size_t)b * N + i0 + lr];
  };

  loadAS(0);   // issued first; latency hides under B/E staging

  // stage B tiles -> LDS (swizzled): 2048 16B-chunks, 8 per thread
  #pragma unroll
  for (int q = 0; q < 8; ++q) {
    const int g   = tid + q * 256;
    const int b   = g >> 8;
    const int c8  = g & 255;
    const int row = c8 >> 2;
    const int sl  = c8 & 3;
    const bf16x8 v = *reinterpret_cast<const bf16x8*>(
        p2b + ((size_t)b * N + j0 + row) * D + sl * 8);
    const int su = sl ^ ((row >> 1) & 3);
    *reinterpret_cast<bf16x8*>(&LB[(((b << 6) + row) << 2 | su) << 3]) = v;
  }
  // stage E: 512 floats (threads 0-127)
  if (tid < 128) {
    const int b = tid >> 4, o = (tid & 15) * 4;
    *reinterpret_cast<f32x4*>(&LE[b * 64 + o]) =
        *reinterpret_cast<const f32x4*>(e2 + (size_t)b * N + j0 + o);
  }

  __syncthreads();

  const int sub = lk ^ ((lr >> 1) & 3);   // B-read swizzle (c*16 keeps bits)

  #pragma unroll
  for (int t = 0; t < 4; ++t) {
    const int i0 = y0 + t * 64 + wid * 16;

    f32x4 acc[4];
    #pragma unroll
    for (int c = 0; c < 4; ++c) acc[c] = f32x4{0.f, 0.f, 0.f, 0.f};

    #pragma unroll
    for (int b = 0; b < B; ++b) {
      bf16x8 Bf[4];
      #pragma unroll
      for (int c = 0; c < 4; ++c)
        Bf[c] = *reinterpret_cast<const bf16x8*>(
            &LB[(((b << 6) + c * 16 + lr) << 2 | sub) << 3]);
      const f32x4 S4 = {Sv[b], Sv[b], Sv[b], Sv[b]};

      #pragma unroll
      for (int c = 0; c < 4; ++c) {
        const f32x4 E4 = *reinterpret_cast<const f32x4*>(
            &LE[b * 64 + c * 16 + lk * 4]);
        // swapped operands: D[col=lr -> i, reg -> j]
        f32x4 tt = __builtin_amdgcn_mfma_f32_16x16x32_bf16(
            Bf[c], A[b], S4, 0, 0, 0);
        #pragma unroll
        for (int r = 0; r < 4; ++r)
          acc[c][r] = fmaf(E4[r], exp2_poly(tt[r]), acc[c][r]);
      }
    }

    if (t < 3) loadAS(t + 1);
    __builtin_amdgcn_sched_barrier(0);   // pin: loads(t+1) before stores(t)

    const int row = i0 + lr;
    #pragma unroll
    for (int c = 0; c < 4; ++c) {
      const int colb = j0 + c * 16 + lk * 4;
      f32x4 v = acc[c];
      #pragma unroll
      for (int r = 0; r < 4; ++r)
        if (row == colb + r) v[r] = 0.1f;
      *reinterpret_cast<f32x4*>(out + (size_t)row * N + colb) = v;
    }
  }
}

extern "C" void kernel_launch(void* const* d_in, const int* in_sizes, int n_in,
                              void* d_out, int out_size, void* d_ws, size_t ws_size,
                              hipStream_t stream) {
  (void)in_sizes; (void)n_in; (void)out_size; (void)ws_size;
  const float* x  = (const float*)d_in[0];
  const float* W1 = (const float*)d_in[1];
  const float* b1 = (const float*)d_in[2];
  const float* W2 = (const float*)d_in[3];
  const float* b2 = (const float*)d_in[4];
  float* out = (float*)d_out;

  char* ws = (char*)d_ws;
  const size_t pbytes = (size_t)B * N * D * sizeof(__bf16);  // 2 MB each
  __bf16* p1b = (__bf16*)ws;
  __bf16* p2b = (__bf16*)(ws + pbytes);
  float*  s1  = (float*)(ws + 2 * pbytes);
  float*  e2  = (float*)(ws + 2 * pbytes + (size_t)B * N * sizeof(float));

  proj_mfma<<<(B * N) / 64, 256, 0, stream>>>(x, W1, b1, W2, b2, p1b, p2b, s1, e2);

  dim3 grid(N / 64, N / 256);
  fused_kernel<<<grid, 256, 0, stream>>>(p1b, p2b, s1, e2, out);
}

// Round 13
// 50.653 us; speedup vs baseline: 7.7822x; 7.7822x over previous
//
#include <hip/hip_runtime.h>
#include <hip/hip_bf16.h>

typedef __bf16 bf16x8 __attribute__((ext_vector_type(8)));
typedef float  f32x4  __attribute__((ext_vector_type(4)));

constexpr int B = 8, N = 4096, T = 128, D = 32;
constexpr float GAMMA = 0.001f;
constexpr float LOG2E = 1.4426950408889634f;
constexpr float K2 = -GAMMA * LOG2E;   // coeff on sq1 / sq2 (log2 domain)
constexpr float M2 = -2.0f * K2;       // coeff on dot

__device__ __forceinline__ float exp2_fast(float t) {
#if __has_builtin(__builtin_amdgcn_exp2f)
  return __builtin_amdgcn_exp2f(t);
#else
  return exp2f(t);
#endif
}

// deg-3 minimax for 2^t on [-2, 0]; abs err ~6.5e-4 (t provably in-range).
__device__ __forceinline__ float exp2_poly(float t) {
  return fmaf(fmaf(fmaf(0.0285860f, t, 0.2107500f), t, 0.6821055f), t,
              0.9993455f);
}

// ---------------------------------------------------------------------------
// Kernel 1 (MFMA proj): unchanged from r3-r12 (~4-5 us).
// ---------------------------------------------------------------------------
__global__ __launch_bounds__(256, 2) void proj_mfma(
    const float* __restrict__ x,  const float* __restrict__ W1,
    const float* __restrict__ b1, const float* __restrict__ W2,
    const float* __restrict__ b2,
    __bf16* __restrict__ p1b, __bf16* __restrict__ p2b,
    float* __restrict__ s1, float* __restrict__ e2) {
  __shared__ bf16x8 wlds[4][4][64];   // 16 KB, frag-ready
  const int tid  = threadIdx.x;
  const int lane = tid & 63;
  const int wid  = tid >> 6;
  const int lr   = lane & 15;
  const int lk   = lane >> 4;
  const int r0   = blockIdx.x * 64 + wid * 16;   // 0 .. B*N-1

  #pragma unroll
  for (int t = 0; t < 4; ++t) {
    const int e  = tid + t * 256;
    const int c  = e >> 8;
    const int s  = (e >> 6) & 3;
    const int ln = e & 63;
    const int llr = ln & 15, llk = ln >> 4;
    const float* Wp = (c < 2) ? W1 : W2;
    const int cc = (c * 16 + llr) & 31;
    bf16x8 v;
    #pragma unroll
    for (int j = 0; j < 8; ++j)
      v[j] = (__bf16)Wp[(s * 32 + llk * 8 + j) * D + cc];
    wlds[c][s][ln] = v;
  }
  __syncthreads();

  bf16x8 wf[4][4];
  #pragma unroll
  for (int c = 0; c < 4; ++c)
    #pragma unroll
    for (int s = 0; s < 4; ++s)
      wf[c][s] = wlds[c][s][lane];

  bf16x8 af[4];
  const float* xr = x + (size_t)(r0 + lr) * T;
  #pragma unroll
  for (int s = 0; s < 4; ++s) {
    const int t0 = s * 32 + lk * 8;
    const f32x4 v0 = *reinterpret_cast<const f32x4*>(xr + t0);
    const f32x4 v1 = *reinterpret_cast<const f32x4*>(xr + t0 + 4);
    #pragma unroll
    for (int j = 0; j < 4; ++j) {
      af[s][j]     = (__bf16)v0[j];
      af[s][4 + j] = (__bf16)v1[j];
    }
  }

  f32x4 pv[4];
  #pragma unroll
  for (int c = 0; c < 4; ++c) {
    const float* bp = (c < 2) ? b1 : b2;
    const float bv = bp[(c * 16 + lr) & 31];
    f32x4 accv = {bv, bv, bv, bv};
    #pragma unroll
    for (int s = 0; s < 4; ++s)
      accv = __builtin_amdgcn_mfma_f32_16x16x32_bf16(af[s], wf[c][s], accv, 0, 0, 0);
    pv[c] = accv;
  }

  #pragma unroll
  for (int c = 0; c < 2; ++c)
    #pragma unroll
    for (int r = 0; r < 4; ++r)
      p1b[(size_t)(r0 + lk * 4 + r) * D + c * 16 + lr] = (__bf16)(M2 * pv[c][r]);
  #pragma unroll
  for (int c = 2; c < 4; ++c)
    #pragma unroll
    for (int r = 0; r < 4; ++r)
      p2b[(size_t)(r0 + lk * 4 + r) * D + (c - 2) * 16 + lr] = (__bf16)pv[c][r];

  float q1[4], q2[4];
  #pragma unroll
  for (int r = 0; r < 4; ++r) {
    q1[r] = fmaf(pv[0][r], pv[0][r], pv[1][r] * pv[1][r]);
    q2[r] = fmaf(pv[2][r], pv[2][r], pv[3][r] * pv[3][r]);
  }
  #pragma unroll
  for (int m = 1; m < 16; m <<= 1)
    #pragma unroll
    for (int r = 0; r < 4; ++r) {
      q1[r] += __shfl_xor(q1[r], m, 64);
      q2[r] += __shfl_xor(q2[r], m, 64);
    }
  if (lr == 0) {
    #pragma unroll
    for (int r = 0; r < 4; ++r) {
      const int row = r0 + lk * 4 + r;
      s1[row] = K2 * q1[r];
      e2[row] = 0.125f * exp2_fast(K2 * q2[r]);
    }
  }
}

// ---------------------------------------------------------------------------
// Kernel 2 v13 = r11 verbatim EXCEPT: swapped MFMA operands + dwordx4 stores.
//   mfma(Bf, A, S4): D lane layout -> row i = i0+lr (one row per lane),
//   cols j = j0 + c*16 + lk*4 + r (4 consecutive) => 4 dwordx4 stores per
//   thread instead of 16 scalar dwords; E read becomes vector f32x4;
//   C-in is broadcast s1[i0+lr].
// No lambdas writing register arrays, no sched_barrier (r12's spill trap).
// ---------------------------------------------------------------------------
__global__ __launch_bounds__(256, 4) void fused_kernel(
    const __bf16* __restrict__ p1b, const __bf16* __restrict__ p2b,
    const float* __restrict__ s1,   const float* __restrict__ e2,
    float* __restrict__ out) {
  __shared__ __align__(16) __bf16 LB[B * 64 * 32];  // 32 KB, swizzled slots
  __shared__ __align__(16) float  LS[B * 64];       // 2 KB
  __shared__ __align__(16) float  LE[B * 64];       // 2 KB

  const int tid  = threadIdx.x;
  const int lane = tid & 63;
  const int wid  = tid >> 6;
  const int j0 = blockIdx.x * 64;                // col base (block)
  const int i0blk = blockIdx.y * 64;             // row base (block)
  const int i0 = i0blk + wid * 16;               // row base (wave)
  const int lr = lane & 15;
  const int lk = lane >> 4;

  // A-fragments, all 8 batches (32 VGPR), issued first
  bf16x8 A[B];
  #pragma unroll
  for (int b = 0; b < B; ++b)
    A[b] = *reinterpret_cast<const bf16x8*>(
        p1b + ((size_t)b * N + i0 + lr) * D + lk * 8);

  // stage B tiles -> LDS (swizzled): 2048 16B-chunks, 8 per thread
  #pragma unroll
  for (int q = 0; q < 8; ++q) {
    const int g   = tid + q * 256;
    const int b   = g >> 8;
    const int c8  = g & 255;
    const int row = c8 >> 2;
    const int sl  = c8 & 3;
    const bf16x8 v = *reinterpret_cast<const bf16x8*>(
        p2b + ((size_t)b * N + j0 + row) * D + sl * 8);
    const int su = sl ^ ((row >> 1) & 3);
    *reinterpret_cast<bf16x8*>(&LB[(((b << 6) + row) << 2 | su) << 3]) = v;
  }
  // stage S (threads 0-127) and E (threads 128-255): 512 floats each
  if (tid < 128) {
    const int b = tid >> 4, o = (tid & 15) * 4;
    *reinterpret_cast<f32x4*>(&LS[b * 64 + o]) =
        *reinterpret_cast<const f32x4*>(s1 + (size_t)b * N + i0blk + o);
  } else {
    const int t2 = tid - 128;
    const int b = t2 >> 4, o = (t2 & 15) * 4;
    *reinterpret_cast<f32x4*>(&LE[b * 64 + o]) =
        *reinterpret_cast<const f32x4*>(e2 + (size_t)b * N + j0 + o);
  }

  __syncthreads();

  // per-lane C-in: K2*sq1 at row i0+lr
  float Sv[B];
  #pragma unroll
  for (int b = 0; b < B; ++b)
    Sv[b] = LS[b * 64 + wid * 16 + lr];

  f32x4 acc[4];
  #pragma unroll
  for (int c = 0; c < 4; ++c) acc[c] = f32x4{0.f, 0.f, 0.f, 0.f};

  const int sub = lk ^ ((lr >> 1) & 3);   // B-read swizzle (c*16 keeps bits)
  #pragma unroll
  for (int b = 0; b < B; ++b) {
    bf16x8 Bf[4];
    #pragma unroll
    for (int c = 0; c < 4; ++c)
      Bf[c] = *reinterpret_cast<const bf16x8*>(
          &LB[(((b << 6) + c * 16 + lr) << 2 | sub) << 3]);
    const f32x4 S4 = {Sv[b], Sv[b], Sv[b], Sv[b]};

    #pragma unroll
    for (int c = 0; c < 4; ++c) {
      // swapped operands: D row index <- Bf rows (j), D col <- A rows (i).
      // lane holds (i = i0+lr, j = j0 + c*16 + lk*4 + r), r = 0..3
      f32x4 t = __builtin_amdgcn_mfma_f32_16x16x32_bf16(
          Bf[c], A[b], S4, 0, 0, 0);
      const f32x4 E4 = *reinterpret_cast<const f32x4*>(
          &LE[b * 64 + c * 16 + lk * 4]);
      #pragma unroll
      for (int r = 0; r < 4; ++r)
        acc[c][r] = fmaf(E4[r], exp2_poly(t[r]), acc[c][r]);
    }
  }

  const int row = i0 + lr;
  #pragma unroll
  for (int c = 0; c < 4; ++c) {
    const int colb = j0 + c * 16 + lk * 4;
    f32x4 v = acc[c];
    #pragma unroll
    for (int r = 0; r < 4; ++r)
      if (row == colb + r) v[r] = 0.1f;
    *reinterpret_cast<f32x4*>(out + (size_t)row * N + colb) = v;
  }
}

extern "C" void kernel_launch(void* const* d_in, const int* in_sizes, int n_in,
                              void* d_out, int out_size, void* d_ws, size_t ws_size,
                              hipStream_t stream) {
  (void)in_sizes; (void)n_in; (void)out_size; (void)ws_size;
  const float* x  = (const float*)d_in[0];
  const float* W1 = (const float*)d_in[1];
  const float* b1 = (const float*)d_in[2];
  const float* W2 = (const float*)d_in[3];
  const float* b2 = (const float*)d_in[4];
  float* out = (float*)d_out;

  char* ws = (char*)d_ws;
  const size_t pbytes = (size_t)B * N * D * sizeof(__bf16);  // 2 MB each
  __bf16* p1b = (__bf16*)ws;
  __bf16* p2b = (__bf16*)(ws + pbytes);
  float*  s1  = (float*)(ws + 2 * pbytes);
  float*  e2  = (float*)(ws + 2 * pbytes + (size_t)B * N * sizeof(float));

  proj_mfma<<<(B * N) / 64, 256, 0, stream>>>(x, W1, b1, W2, b2, p1b, p2b, s1, e2);

  dim3 grid(N / 64, N / 64);
  fused_kernel<<<grid, 256, 0, stream>>>(p1b, p2b, s1, e2, out);
}